// Round 14
// baseline (329.359 us; speedup 1.0000x reference)
//
#include <hip/hip_runtime.h>
#include <hip/hip_bf16.h>
#include <math.h>

// Problem dims
#define BB 16
#define NN 100
#define MAXNB 10
#define NBONDS 120
#define AF 82
#define BF 6
#define HH 300
#define BIN 11
#define DEPTH 3
#define KTOP 80

typedef __attribute__((ext_vector_type(8))) short short8;
typedef __attribute__((ext_vector_type(4))) float floatx4;

__device__ __forceinline__ unsigned short f2bf(float f) {
    unsigned int u = __float_as_uint(f);
    unsigned int r = (u + 0x7FFFu + ((u >> 16) & 1u)) >> 16;
    return (unsigned short)r;
}
__device__ __forceinline__ float bf2f(unsigned short h) {
    return __uint_as_float(((unsigned int)h) << 16);
}

// W-frag table offsets (in shorts), identical layout for hi and lo planes.
#define O_WATOM 0        // kc=3
#define O_WNB   29184    // kc=1
#define O_U2B   38912    // kc=1
#define O_WNA   48640    // kc=10
#define O_U2A   145920
#define O_WSELF 243200
#define O_U1A   340480
#define O_U1B   437760
#define O_WATT  535040
#define O_WPL   632320
#define O_WPG   729600

// ---------------------------------------------------------------------------
// Fused prep:
//   z<11  -> weight matrix z into hi/lo bf16 B-fragment tables
//   z==11 -> convert fatoms/fbonds to hi/lo bf16 row pairs
//   z==12 -> pair-stage tables: binary_feats -> BINBF; Wbin -> WBF (x2)
// ---------------------------------------------------------------------------
__global__ __launch_bounds__(256) void k_prep(
    const float* __restrict__ s0, const float* __restrict__ s1,
    const float* __restrict__ s2, const float* __restrict__ s3,
    const float* __restrict__ s4, const float* __restrict__ s5,
    const float* __restrict__ s6, const float* __restrict__ s7,
    const float* __restrict__ s8, const float* __restrict__ s9,
    const float* __restrict__ s10,
    unsigned short* __restrict__ WTh, unsigned short* __restrict__ WTl,
    const float* __restrict__ fatoms, const float* __restrict__ fbonds,
    unsigned short* __restrict__ fatomsbf, unsigned short* __restrict__ fbondsbf,
    const float* __restrict__ bin, unsigned short* __restrict__ BINBF,
    const float* __restrict__ Wbin0, const float* __restrict__ Wbin1,
    unsigned short* __restrict__ WBF0, unsigned short* __restrict__ WBF1)
{
    const int z = blockIdx.z;
    if (z == 11) {
        int idx = blockIdx.x * 256 + threadIdx.x;
        if (idx < 1600 * 96) {
            int r = idx / 96, c = idx - r * 96;
            float f = (c < AF) ? fatoms[r * AF + c] : 0.f;
            unsigned short hb = f2bf(f);
            fatomsbf[r * 192 + c]      = hb;
            fatomsbf[r * 192 + 96 + c] = f2bf(f - bf2f(hb));
        } else {
            int i2 = idx - 1600 * 96;
            if (i2 < 1920 * 32) {
                int r = i2 / 32, c = i2 - r * 32;
                float f = (c < BF) ? fbonds[r * BF + c] : 0.f;
                unsigned short hb = f2bf(f);
                fbondsbf[r * 64 + c]      = hb;
                fbondsbf[r * 64 + 32 + c] = f2bf(f - bf2f(hb));
            }
        }
        return;
    }
    if (z == 12) {
        const int bx = blockIdx.x;
        if (bx < 625) {
            int p = bx * 256 + threadIdx.x;
            if (p < BB * NN * NN) {
                const float* src = bin + (size_t)p * BIN;
                unsigned short tmp[16];
#pragma unroll
                for (int k = 0; k < BIN; k++) tmp[k] = f2bf(src[k]);
#pragma unroll
                for (int k = BIN; k < 16; k++) tmp[k] = 0;
                *(uint4*)(BINBF + (size_t)p * 16) = *(uint4*)tmp;
                *(uint4*)(BINBF + (size_t)p * 16 + 8) = *(uint4*)(tmp + 8);
            }
        } else if (bx < 663) {
            int zb = bx - 625;             // 0..37
            const float* src = (zb >= 19) ? Wbin1 : Wbin0;
            unsigned short* dst = (zb >= 19) ? WBF1 : WBF0;
            int idx = (zb % 19) * 256 + threadIdx.x;
            int jj = idx & 7;
            int koct = (idx >> 3) & 1;
            int n = (idx >> 4) & 15;
            int ch = idx >> 8;
            int k = koct * 8 + jj;
            int h = ch * 16 + n;
            float f = (k < BIN && h < 300) ? src[k * 300 + h] : 0.f;
            dst[idx] = f2bf(f);
        }
        return;
    }
    const float* src; int K, kc, off;
    switch (z) {
        case 0:  src = s0;  K = AF;  kc = 3;  off = O_WATOM; break;
        case 1:  src = s1;  K = BF;  kc = 1;  off = O_WNB;   break;
        case 2:  src = s2;  K = BF;  kc = 1;  off = O_U2B;   break;
        case 3:  src = s3;  K = HH;  kc = 10; off = O_WNA;   break;
        case 4:  src = s4;  K = HH;  kc = 10; off = O_U2A;   break;
        case 5:  src = s5;  K = HH;  kc = 10; off = O_WSELF; break;
        case 6:  src = s6;  K = HH;  kc = 10; off = O_U1A;   break;
        case 7:  src = s7;  K = HH;  kc = 10; off = O_U1B;   break;
        case 8:  src = s8;  K = HH;  kc = 10; off = O_WATT;  break;
        case 9:  src = s9;  K = HH;  kc = 10; off = O_WPL;   break;
        default: src = s10; K = HH;  kc = 10; off = O_WPG;   break;
    }
    const int lim = 9728 * kc;
    int i = blockIdx.x * 256 + threadIdx.x;
    if (i < lim) {
        int jj = i & 7;
        int lane = (i >> 3) & 63;
        int rem = i >> 9;
        int kci = rem % kc;
        int ct = rem / kc;
        int k = kci * 32 + (lane >> 4) * 8 + jj;
        int col = ct * 16 + (lane & 15);
        float f = (k < K && col < 300) ? src[k * 300 + col] : 0.f;
        unsigned short hb = f2bf(f);
        WTh[off + i] = hb;
        WTl[off + i] = f2bf(f - bf2f(hb));
    }
}

// ---------------------------------------------------------------------------
// bf16x3 MFMA GEMM core. Per k-chunk: acc += ah*wl + al*wh + ah*wh.
// ---------------------------------------------------------------------------
__device__ __forceinline__ void gemm_core(
    const unsigned short* __restrict__ A, int lda, int kc, int M,
    const unsigned short* __restrict__ wthB, const unsigned short* __restrict__ wtlB,
    float* __restrict__ C, int ldc,
    const float* __restrict__ bias,
    const float* __restrict__ Add, int ldAdd, int addOff,
    int act, unsigned short* __restrict__ Cbf,
    int row0, int gcolBase)
{
    __shared__ unsigned short sa[16 * 648];
    if (row0 >= M) return;                       // block-uniform
    const int tid = threadIdx.x;
    const int lane = tid & 63;
    const int wid = tid >> 6;
    const int sR = kc * 64 + 8;

    {
        const uint4* Ag = (const uint4*)A;
        uint4* sa4 = (uint4*)sa;
        const int q4 = kc * 8;
        const int lda4 = lda >> 3;
        const int sR4 = q4 + 1;
        for (int i = tid; i < 16 * q4; i += 256) {
            int r = i / q4, q = i - r * q4;
            sa4[r * sR4 + q] = Ag[(size_t)(row0 + r) * lda4 + q];
        }
    }
    __syncthreads();

    const int ct = blockIdx.y * 4 + wid;
    if (ct >= 19) return;

    const int m = lane & 15;
    const int rq = lane >> 4;
    const int koct8 = rq * 8;
    const unsigned short* wth = wthB + (size_t)ct * kc * 512;
    const unsigned short* wtl = wtlB + (size_t)ct * kc * 512;

    floatx4 acc = {0.f, 0.f, 0.f, 0.f};
    for (int kci = 0; kci < kc; kci++) {
        short8 ah = *(const short8*)(sa + m * sR + kci * 32 + koct8);
        short8 al = *(const short8*)(sa + m * sR + kc * 32 + kci * 32 + koct8);
        short8 wh = *(const short8*)(wth + (kci * 64 + lane) * 8);
        short8 wl = *(const short8*)(wtl + (kci * 64 + lane) * 8);
        acc = __builtin_amdgcn_mfma_f32_16x16x32_bf16(ah, wl, acc, 0, 0, 0);
        acc = __builtin_amdgcn_mfma_f32_16x16x32_bf16(al, wh, acc, 0, 0, 0);
        acc = __builtin_amdgcn_mfma_f32_16x16x32_bf16(ah, wh, acc, 0, 0, 0);
    }

    const int col = ct * 16 + m;
    if (col < 300) {
        const float bv = bias ? bias[col] : 0.f;
        const int gcol = gcolBase + col;
#pragma unroll
        for (int r = 0; r < 4; r++) {
            const int grow = row0 + rq * 4 + r;
            float v = acc[r] + bv;
            if (Add) v += Add[(size_t)grow * ldAdd + addOff + col];
            if (act) v = fmaxf(v, 0.f);
            if (C) C[(size_t)grow * ldc + gcol] = v;
            if (Cbf) {
                unsigned short hb = f2bf(v);
                Cbf[(size_t)grow * 640 + col]       = hb;
                Cbf[(size_t)grow * 640 + 320 + col] = f2bf(v - bf2f(hb));
            }
        }
    }
}

// Grid: (rowTilesPadded8, 5, nW) — same-row blocks land on one XCD.
__global__ __launch_bounds__(256) void k_gemm_mfma(
    const unsigned short* __restrict__ A, int lda, int kc, int M,
    const unsigned short* __restrict__ WTh, const unsigned short* __restrict__ WTl,
    int wtStride,
    float* __restrict__ C, int ldc,
    const float* __restrict__ bias,
    const float* __restrict__ Add, int ldAdd, int addOff,
    int act, unsigned short* __restrict__ Cbf)
{
    const int widx = blockIdx.z;
    gemm_core(A, lda, kc, M,
              WTh + (size_t)widx * wtStride, WTl + (size_t)widx * wtStride,
              C, ldc, bias, Add, ldAdd, addOff, act, Cbf,
              blockIdx.x * 16, widx * 300);
}

// Fused opening GEMMs: z=0 -> h = relu(fatoms@W_atom) -> hbf;
// z=1,2 -> FB = fbonds @ [W_nei_bond | W_U2b] -> f32 ld 600.
__global__ __launch_bounds__(256) void k_gemm_first(
    const unsigned short* __restrict__ fatomsbf,
    const unsigned short* __restrict__ fbondsbf,
    const unsigned short* __restrict__ WTh, const unsigned short* __restrict__ WTl,
    unsigned short* __restrict__ hbf, float* __restrict__ FBout)
{
    const int z = blockIdx.z;
    if (z == 0) {
        gemm_core(fatomsbf, 192, 3, 1600,
                  WTh + O_WATOM, WTl + O_WATOM,
                  nullptr, 0, nullptr, nullptr, 0, 0, 1, hbf,
                  blockIdx.x * 16, 0);
    } else {
        const int w = z - 1;
        gemm_core(fbondsbf, 64, 1, 1920,
                  WTh + O_WNB + w * 9728, WTl + O_WNB + w * 9728,
                  FBout, 600, nullptr, nullptr, 0, 0, 0, nullptr,
                  blockIdx.x * 16, w * 300);
    }
}

// ---------------------------------------------------------------------------
// k_neighbor: float4-vectorized, 4 bn per block; hi/lo bf16 outputs.
// XCD swizzle: batch = bx&15.
// ---------------------------------------------------------------------------
__global__ __launch_bounds__(320) void k_neighbor(
    const float* __restrict__ HW, const float* __restrict__ FB,
    const int* __restrict__ atom_nb, const int* __restrict__ bond_nb,
    const float* __restrict__ mask_neis, const float* __restrict__ mask_atoms,
    const float* __restrict__ b_U2,
    unsigned short* __restrict__ localbf, unsigned short* __restrict__ nlbf)
{
    __shared__ int   sAn[4][MAXNB];
    __shared__ int   sBd[4][MAXNB];
    __shared__ float sM[4][MAXNB];
    const int tx = threadIdx.x;
    const int ty = threadIdx.y;
    const int bx = blockIdx.x;
    const int bn0 = ((bx & 15) * 25 + (bx >> 4)) * 4;
    const int flat = ty * 80 + tx;

    if (flat < 40)        sAn[flat / 10][flat % 10] = atom_nb[(bn0 + flat / 10) * MAXNB + flat % 10];
    else if (flat < 80)  { int f = flat - 40; sBd[f / 10][f % 10] = bond_nb[(bn0 + f / 10) * MAXNB + f % 10]; }
    else if (flat < 120) { int f = flat - 80; sM[f / 10][f % 10]  = mask_neis[(bn0 + f / 10) * MAXNB + f % 10]; }
    __syncthreads();

    if (tx >= 75) return;
    const int bn = bn0 + ty;
    const int b = bn / NN;
    const int h4 = tx;

    const float4* HW4 = (const float4*)HW;
    const float4* FB4 = (const float4*)FB;
    const float4 bu = ((const float4*)b_U2)[h4];

    float4 fnei = make_float4(0.f,0.f,0.f,0.f);
    float4 nls  = fnei;
#pragma unroll
    for (int k = 0; k < MAXNB; k++) {
        const int an = sAn[ty][k];
        const int bd = sBd[ty][k];
        const float m = sM[ty][k];
        const float4* hr = HW4 + (size_t)(b * NN + an) * 300;
        const float4* fr = FB4 + (size_t)(b * NBONDS + bd) * 150;
        float4 ha = hr[h4];
        float4 hu = hr[75 + h4];
        float4 fa = fr[h4];
        float4 fu = fr[75 + h4];
        fnei.x = fmaf(m, ha.x * fa.x, fnei.x);
        fnei.y = fmaf(m, ha.y * fa.y, fnei.y);
        fnei.z = fmaf(m, ha.z * fa.z, fnei.z);
        fnei.w = fmaf(m, ha.w * fa.w, fnei.w);
        float ux = hu.x + fu.x + bu.x;
        float uy = hu.y + fu.y + bu.y;
        float uz = hu.z + fu.z + bu.z;
        float uw = hu.w + fu.w + bu.w;
        nls.x = fmaf(m, fmaxf(ux, 0.f), nls.x);
        nls.y = fmaf(m, fmaxf(uy, 0.f), nls.y);
        nls.z = fmaf(m, fmaxf(uz, 0.f), nls.z);
        nls.w = fmaf(m, fmaxf(uw, 0.f), nls.w);
    }
    const float ma = mask_atoms[bn];
    const float4 sf = HW4[(size_t)bn * 300 + 150 + h4];
    float lv[4], nv[4];
    lv[0] = fnei.x * sf.x * ma; lv[1] = fnei.y * sf.y * ma;
    lv[2] = fnei.z * sf.z * ma; lv[3] = fnei.w * sf.w * ma;
    nv[0] = nls.x; nv[1] = nls.y; nv[2] = nls.z; nv[3] = nls.w;

    ushort4 lh, ll, nh, nl2;
    unsigned short* lhp = (unsigned short*)&lh;
    unsigned short* llp = (unsigned short*)&ll;
    unsigned short* nhp = (unsigned short*)&nh;
    unsigned short* nlp = (unsigned short*)&nl2;
#pragma unroll
    for (int c = 0; c < 4; c++) {
        unsigned short hb = f2bf(lv[c]);
        lhp[c] = hb; llp[c] = f2bf(lv[c] - bf2f(hb));
        unsigned short nb = f2bf(nv[c]);
        nhp[c] = nb; nlp[c] = f2bf(nv[c] - bf2f(nb));
    }
    *(ushort4*)(localbf + (size_t)bn * 640 + h4 * 4)       = lh;
    *(ushort4*)(localbf + (size_t)bn * 640 + 320 + h4 * 4) = ll;
    *(ushort4*)(nlbf    + (size_t)bn * 640 + h4 * 4)       = nh;
    *(ushort4*)(nlbf    + (size_t)bn * 640 + 320 + h4 * 4) = nl2;
}

// ---------------------------------------------------------------------------
// k_pair: batch-major grid (XCD-pinned); LDS stride 308 (2-way aliasing only).
// ---------------------------------------------------------------------------
__global__ __launch_bounds__(256) void k_pair(
    const float* __restrict__ R, int ldr,
    const unsigned short* __restrict__ BINBF,
    const unsigned short* __restrict__ WBF,
    const float* __restrict__ bvec,
    const float* __restrict__ Wscore, const float* __restrict__ bscore,
    float* __restrict__ outp, int mode)
{
    __shared__ float sLi[16 * 308];
    __shared__ float sLj[16 * 308];

    const int b  = blockIdx.x;                 // XCD = b & 7
    const int i0 = blockIdx.y * 16;
    const int j0 = blockIdx.z * 16;
    const int tid = threadIdx.x;
    const int lane = tid & 63;
    const int wid = tid >> 6;

    for (int idx = tid; idx < 16 * 308; idx += 256) {
        int r = idx / 308;
        int c = idx - r * 308;
        float vi = 0.f, vj = 0.f;
        if (c < 300) {
            if (i0 + r < NN) vi = R[(size_t)(b * NN + i0 + r) * ldr + c] + bvec[c];
            if (j0 + r < NN) vj = R[(size_t)(b * NN + j0 + r) * ldr + c];
        }
        sLi[idx] = vi;
        sLj[idx] = vj;
    }

    const int m = lane & 15;
    const int koct = lane >> 4;
    short8 afrag[4];
#pragma unroll
    for (int g = 0; g < 4; g++) {
        int ii = i0 + wid * 4 + g; if (ii > NN - 1) ii = NN - 1;
        int jj2 = j0 + m;          if (jj2 > NN - 1) jj2 = NN - 1;
        const size_t pidx = (size_t)((b * NN + ii) * NN + jj2);
        afrag[g] = *(const short8*)(BINBF + pidx * 16 + (koct & 1) * 8);
        if (koct >= 2) afrag[g] = short8{0,0,0,0,0,0,0,0};
    }
    __syncthreads();

    const int n = lane & 15;
    const int rquad = lane >> 4;
    const floatx4 zero = {0.f, 0.f, 0.f, 0.f};
    float su[4][4];
#pragma unroll
    for (int g = 0; g < 4; g++)
#pragma unroll
        for (int r = 0; r < 4; r++) su[g][r] = 0.f;

    for (int ch = 0; ch < 19; ch++) {
        const int h0 = ch * 16;
        short8 bfrag = {0,0,0,0,0,0,0,0};
        if (lane < 32)
            bfrag = *(const short8*)(WBF + ch * 256 + (n * 2 + koct) * 8);
        float wsv = 0.f;
        if (h0 + n < 300) wsv = Wscore[h0 + n];
#pragma unroll
        for (int g = 0; g < 4; g++) {
            floatx4 P = __builtin_amdgcn_mfma_f32_16x16x32_bf16(
                afrag[g], bfrag, zero, 0, 0, 0);
            const float liv = sLi[(wid * 4 + g) * 308 + h0 + n];
#pragma unroll
            for (int r = 0; r < 4; r++) {
                const float ljv = sLj[(rquad * 4 + r) * 308 + h0 + n];
                float u = P[r] + liv + ljv;
                su[g][r] = fmaf(fmaxf(u, 0.f), wsv, su[g][r]);
            }
        }
    }

    const float bs = bscore[0];
#pragma unroll
    for (int g = 0; g < 4; g++) {
#pragma unroll
        for (int r = 0; r < 4; r++) {
            float v = su[g][r];
            v += __shfl_xor(v, 1);
            v += __shfl_xor(v, 2);
            v += __shfl_xor(v, 4);
            v += __shfl_xor(v, 8);
            if (n == 0) {
                const int i = i0 + wid * 4 + g;
                const int j = j0 + rquad * 4 + r;
                if (i < NN && j < NN) {
                    float s = v + bs;
                    outp[(size_t)(b * NN + i) * NN + j] =
                        (mode == 0) ? (1.f / (1.f + expf(-s))) : s;
                }
            }
        }
    }
}

// ---------------------------------------------------------------------------
// Fused ctx + LPG GEMM. Grid (16 batches, 7 i-tiles), 256 threads.
// Phase 1: ctx rows i0..i0+15 (f32) -> bf16 hi/lo A-tile in LDS.
// Phase 2: LPG tile = ctx @ W_pg + LL[:,300:600] (bf16x3 MFMA from LDS A).
// ---------------------------------------------------------------------------
__global__ __launch_bounds__(256) void k_ctxlpg(
    const float* __restrict__ att, const unsigned short* __restrict__ localbf,
    const unsigned short* __restrict__ WThPG, const unsigned short* __restrict__ WTlPG,
    const float* __restrict__ LL, float* __restrict__ LPG)
{
    __shared__ float sAtt[16 * 100];             // 6.4 KB
    __shared__ unsigned short sa[16 * 648];      // 20.7 KB (A-tile, gemm layout)
    const int b  = blockIdx.x;                   // XCD = b & 7
    const int i0 = blockIdx.y * 16;
    const int tid = threadIdx.x;
    const int lane = tid & 63;
    const int wid = tid >> 6;

    // stage att tile (zero for i >= NN)
    for (int idx = tid; idx < 1600; idx += 256) {
        int ii = idx / 100, j = idx - ii * 100;
        float v = 0.f;
        if (i0 + ii < NN) v = att[(size_t)(b * NN + i0 + ii) * NN + j];
        sAtt[idx] = v;
    }
    __syncthreads();

    // phase 1: ctx for h = tid (+256); write bf16 hi/lo into A-tile
#pragma unroll
    for (int hbase = 0; hbase < 2; hbase++) {
        const int h = tid + hbase * 256;
        if (h < 300) {
            float acc[16];
#pragma unroll
            for (int i = 0; i < 16; i++) acc[i] = 0.f;
            for (int j = 0; j < NN; j++) {
                const unsigned short* lr = localbf + (size_t)(b * NN + j) * 640;
                float lv = bf2f(lr[h]) + bf2f(lr[320 + h]);
#pragma unroll
                for (int i = 0; i < 16; i++)
                    acc[i] = fmaf(sAtt[i * 100 + j], lv, acc[i]);
            }
#pragma unroll
            for (int i = 0; i < 16; i++) {
                unsigned short hb = f2bf(acc[i]);
                sa[i * 648 + h] = hb;
                sa[i * 648 + 320 + h] = f2bf(acc[i] - bf2f(hb));
            }
        }
    }
    // zero-pad k columns 300..319 (hi and lo planes)
    if (tid < 20) {
#pragma unroll
        for (int i = 0; i < 16; i++) {
            sa[i * 648 + 300 + tid] = 0;
            sa[i * 648 + 320 + 300 + tid] = 0;
        }
    }
    __syncthreads();

    // phase 2: LPG tile = ctx @ W_pg + LL[:,300:600]
    const int m = lane & 15;
    const int rq = lane >> 4;
    const int koct8 = rq * 8;
    for (int ct = wid; ct < 19; ct += 4) {
        const unsigned short* wth = WThPG + (size_t)ct * 10 * 512;
        const unsigned short* wtl = WTlPG + (size_t)ct * 10 * 512;
        floatx4 acc = {0.f, 0.f, 0.f, 0.f};
        for (int kci = 0; kci < 10; kci++) {
            short8 ah = *(const short8*)(sa + m * 648 + kci * 32 + koct8);
            short8 al = *(const short8*)(sa + m * 648 + 320 + kci * 32 + koct8);
            short8 wh = *(const short8*)(wth + (kci * 64 + lane) * 8);
            short8 wl = *(const short8*)(wtl + (kci * 64 + lane) * 8);
            acc = __builtin_amdgcn_mfma_f32_16x16x32_bf16(ah, wl, acc, 0, 0, 0);
            acc = __builtin_amdgcn_mfma_f32_16x16x32_bf16(al, wh, acc, 0, 0, 0);
            acc = __builtin_amdgcn_mfma_f32_16x16x32_bf16(ah, wh, acc, 0, 0, 0);
        }
        const int col = ct * 16 + m;
        if (col < 300) {
#pragma unroll
            for (int r = 0; r < 4; r++) {
                const int i = i0 + rq * 4 + r;
                if (i < NN) {
                    const int grow = b * NN + i;
                    LPG[(size_t)grow * 300 + col] =
                        acc[r] + LL[(size_t)grow * 600 + 300 + col];
                }
            }
        }
    }
}

// ---------------------------------------------------------------------------
// Top-K: 1024 threads/block, per-wave histograms, wave-parallel suffix-scan.
// ---------------------------------------------------------------------------
__global__ __launch_bounds__(1024) void k_topk(
    const float* __restrict__ scores, float* __restrict__ topk_out)
{
    const int b = blockIdx.x;
    const int tid = threadIdx.x;
    const int wid = tid >> 6;
    const int lane = tid & 63;
    const float* sc = scores + (size_t)b * (NN * NN);

    __shared__ unsigned int skey[NN * NN];
    __shared__ unsigned int whist[16 * 256];
    __shared__ unsigned int hist[256];
    __shared__ unsigned int candU[KTOP];
    __shared__ int candI[KTOP];
    __shared__ int cntG;
    __shared__ int curMin;
    __shared__ unsigned int sh_pref, sh_mask;
    __shared__ int sh_kRem;
    __shared__ int sh_last;

    for (int idx = tid; idx < NN * NN; idx += 1024) {
        unsigned int u = __float_as_uint(sc[idx]);
        u = (u & 0x80000000u) ? ~u : (u | 0x80000000u);
        skey[idx] = u;
    }
    if (tid == 0) {
        sh_pref = 0u; sh_mask = 0u; sh_kRem = KTOP; cntG = 0; sh_last = -1;
    }
    __syncthreads();

    for (int pass = 0; pass < 4; pass++) {
        const int shift = 24 - 8 * pass;
        unsigned int* wh = whist + (wid << 8);
        wh[lane] = 0u; wh[lane + 64] = 0u; wh[lane + 128] = 0u; wh[lane + 192] = 0u;
        __syncthreads();
        const unsigned int pref = sh_pref, mask = sh_mask;
        for (int idx = tid; idx < NN * NN; idx += 1024) {
            unsigned int u = skey[idx];
            if ((u & mask) == pref)
                atomicAdd(&wh[(u >> shift) & 255u], 1u);
        }
        __syncthreads();
        if (tid < 256) {
            unsigned int s = 0u;
#pragma unroll
            for (int w = 0; w < 16; w++) s += whist[(w << 8) | tid];
            hist[tid] = s;
        }
        __syncthreads();
        if (wid == 0) {
            unsigned int h0 = hist[lane * 4 + 0];
            unsigned int h1 = hist[lane * 4 + 1];
            unsigned int h2 = hist[lane * 4 + 2];
            unsigned int h3 = hist[lane * 4 + 3];
            unsigned int own = h0 + h1 + h2 + h3;
            unsigned int suf = own;
#pragma unroll
            for (int off = 1; off < 64; off <<= 1) {
                unsigned int v = __shfl_down(suf, off);
                if (lane + off < 64) suf += v;
            }
            const int k = sh_kRem;
            const unsigned int above = suf - own;
            if (above < (unsigned int)k && suf >= (unsigned int)k) {
                unsigned int c = above, hb; int bsel;
                c += h3;
                if ((int)c >= k) { bsel = lane * 4 + 3; hb = h3; }
                else { c += h2;
                    if ((int)c >= k) { bsel = lane * 4 + 2; hb = h2; }
                    else { c += h1;
                        if ((int)c >= k) { bsel = lane * 4 + 1; hb = h1; }
                        else { c += h0; bsel = lane * 4; hb = h0; } } }
                sh_kRem = k - (int)(c - hb);
                sh_pref = pref | ((unsigned int)bsel << shift);
                sh_mask = mask | (0xFFu << shift);
            }
        }
        __syncthreads();
    }
    const unsigned int T = sh_pref;

    for (int idx = tid; idx < NN * NN; idx += 1024) {
        unsigned int u = skey[idx];
        if (u > T) {
            int pos = atomicAdd(&cntG, 1);
            candU[pos] = u;
            candI[pos] = idx;
        }
    }
    __syncthreads();
    const int needE = KTOP - cntG;

    for (int e = 0; e < needE; e++) {
        if (tid == 0) curMin = 0x7fffffff;
        __syncthreads();
        const int last = sh_last;
        for (int idx = tid; idx < NN * NN; idx += 1024) {
            if (skey[idx] == T && idx > last)
                atomicMin(&curMin, idx);
        }
        __syncthreads();
        if (tid == 0) {
            candU[cntG + e] = T;
            candI[cntG + e] = curMin;
            sh_last = curMin;
        }
        __syncthreads();
    }

    if (tid < KTOP) {
        const unsigned int mu = candU[tid];
        const int mi = candI[tid];
        int rank = 0;
        for (int o = 0; o < KTOP; o++) {
            unsigned int ou = candU[o];
            int oi = candI[o];
            if (ou > mu || (ou == mu && oi < mi)) rank++;
        }
        topk_out[b * KTOP + rank] = (float)mi;
    }
}

// ---------------------------------------------------------------------------
extern "C" void kernel_launch(void* const* d_in, const int* in_sizes, int n_in,
                              void* d_out, int out_size, void* d_ws, size_t ws_size,
                              hipStream_t stream) {
    const float* fatoms       = (const float*)d_in[0];
    const float* fbonds       = (const float*)d_in[1];
    const int*   atom_nb      = (const int*)d_in[2];
    const int*   bond_nb      = (const int*)d_in[3];
    const float* binary_feats = (const float*)d_in[6];
    const float* mask_neis    = (const float*)d_in[7];
    const float* mask_atoms   = (const float*)d_in[8];
    const float* W_atom       = (const float*)d_in[10];
    const float* W_nei_atom   = (const float*)d_in[11];
    const float* W_nei_bond   = (const float*)d_in[12];
    const float* W_self       = (const float*)d_in[13];
    const float* W_U2         = (const float*)d_in[14];
    const float* b_U2         = (const float*)d_in[15];
    const float* W_U1         = (const float*)d_in[16];
    const float* b_U1         = (const float*)d_in[17];
    const float* W_att_local  = (const float*)d_in[18];
    const float* W_att_bin    = (const float*)d_in[19];
    const float* b_att        = (const float*)d_in[20];
    const float* W_att_score  = (const float*)d_in[21];
    const float* b_att_score  = (const float*)d_in[22];
    const float* W_pl         = (const float*)d_in[23];
    const float* W_pg         = (const float*)d_in[24];
    const float* W_pb         = (const float*)d_in[25];
    const float* b_p          = (const float*)d_in[26];
    const float* W_out        = (const float*)d_in[27];
    const float* b_out        = (const float*)d_in[28];

    float* ws = (float*)d_ws;
    // f32 slots
    float* HW  = ws;                         // 1,920,000 f (1600 x 1200)
    float* FB  = HW + 1920000;               // 1,152,000 f (1920 x 600)
    float* LL  = FB + 1152000;               //   960,000 f (1600 x 600)
    float* LPG = LL + 960000;                //   480,000 f (1600 x 300)
    float* att = LPG + 480000;               //   160,000 f
    // shorts region
    unsigned short* S0       = (unsigned short*)(ws + 4672000);
    unsigned short* hbf      = S0;                         // 1,024,000
    unsigned short* nlbf     = S0 + 1024000;               // 1,024,000
    unsigned short* localbf  = S0 + 2048000;               // 1,024,000
    unsigned short* WTh      = S0 + 3072000;               //   826,880
    unsigned short* WTl      = S0 + 3898880;               //   826,880
    unsigned short* BINBF    = S0 + 4725760;               // 2,560,000
    unsigned short* WBF_att  = S0 + 7285760;               //     4,864
    unsigned short* WBF_fin  = S0 + 7290624;               //     4,864
    unsigned short* fatomsbf = S0 + 7295488;               //   307,200
    unsigned short* fbondsbf = S0 + 7602688;               //   122,880

    float* out = (float*)d_out;
    float* topk_out = out + (size_t)BB * NN * NN;

    // single fused prep: weight tables (z<11) + input conv (z=11) + pair tables (z=12)
    k_prep<<<dim3(840, 1, 13), 256, 0, stream>>>(
        W_atom, W_nei_bond, W_U2 + 300 * 300, W_nei_atom, W_U2, W_self,
        W_U1, W_U1 + 300 * 300, W_att_local, W_pl, W_pg, WTh, WTl,
        fatoms, fbonds, fatomsbf, fbondsbf,
        binary_feats, BINBF, W_att_bin, W_pb, WBF_att, WBF_fin);

    // fused opening GEMMs: h -> hbf (z=0); FB (z=1,2)
    k_gemm_first<<<dim3(120, 5, 3), 256, 0, stream>>>(
        fatomsbf, fbondsbf, WTh, WTl, hbf, FB);

    for (int d = 0; d < DEPTH; d++) {
        int nW = (d == DEPTH - 1) ? 3 : 4;
        // HW = h @ [W_nei_atom | W_U2a | W_self | W_U1a] -> f32 ld 1200
        k_gemm_mfma<<<dim3(104, 5, nW), 256, 0, stream>>>(
            hbf, 640, 10, 1600, WTh + O_WNA, WTl + O_WNA, 97280,
            HW, 1200, nullptr, nullptr, 0, 0, 0, nullptr);
        // neighbor aggregate -> localbf, nlbf (hi/lo); batch-XCD swizzled
        k_neighbor<<<dim3(400), dim3(80, 4), 0, stream>>>(
            HW, FB, atom_nb, bond_nb, mask_neis, mask_atoms, b_U2,
            localbf, nlbf);
        if (d < DEPTH - 1) {
            // h = relu(HW[:,900:1200] + nl @ W_U1b + b_U1) -> hbf
            k_gemm_mfma<<<dim3(104, 5, 1), 256, 0, stream>>>(
                nlbf, 640, 10, 1600, WTh + O_U1B, WTl + O_U1B, 0,
                nullptr, 0, b_U1, HW, 1200, 900, 1, hbf);
        }
    }

    // LL = local @ [W_att_local | W_pl] -> f32 ld 600
    k_gemm_mfma<<<dim3(104, 5, 2), 256, 0, stream>>>(
        localbf, 640, 10, 1600, WTh + O_WATT, WTl + O_WATT, 97280,
        LL, 600, nullptr, nullptr, 0, 0, 0, nullptr);

    // att[b,i,j] — pair kernel, batch-major grid (XCD-pinned)
    k_pair<<<dim3(16, 7, 7), 256, 0, stream>>>(
        LL, 600, BINBF, WBF_att, b_att, W_att_score, b_att_score,
        att, 0);

    // fused ctx + LPG GEMM (no ctxbf round-trip)
    k_ctxlpg<<<dim3(16, 7), 256, 0, stream>>>(
        att, localbf, WTh + O_WPG, WTl + O_WPG, LL, LPG);

    // pair scores — pair kernel, batch-major grid (XCD-pinned)
    k_pair<<<dim3(16, 7, 7), 256, 0, stream>>>(
        LPG, 300, BINBF, WBF_fin, b_p, W_out, b_out,
        out, 1);

    // top-k indices per batch (as float values)
    k_topk<<<dim3(BB), 1024, 0, stream>>>(out, topk_out);
}

// Round 15
// 294.956 us; speedup vs baseline: 1.1166x; 1.1166x over previous
//
#include <hip/hip_runtime.h>
#include <hip/hip_bf16.h>
#include <math.h>

// Problem dims
#define BB 16
#define NN 100
#define MAXNB 10
#define NBONDS 120
#define AF 82
#define BF 6
#define HH 300
#define BIN 11
#define DEPTH 3
#define KTOP 80

typedef __attribute__((ext_vector_type(8))) short short8;
typedef __attribute__((ext_vector_type(4))) float floatx4;

__device__ __forceinline__ unsigned short f2bf(float f) {
    unsigned int u = __float_as_uint(f);
    unsigned int r = (u + 0x7FFFu + ((u >> 16) & 1u)) >> 16;
    return (unsigned short)r;
}
__device__ __forceinline__ float bf2f(unsigned short h) {
    return __uint_as_float(((unsigned int)h) << 16);
}

// W-frag table offsets (in shorts), identical layout for hi and lo planes.
#define O_WATOM 0        // kc=3
#define O_WNB   29184    // kc=1
#define O_U2B   38912    // kc=1
#define O_WNA   48640    // kc=10
#define O_U2A   145920
#define O_WSELF 243200
#define O_U1A   340480
#define O_U1B   437760
#define O_WATT  535040
#define O_WPL   632320
#define O_WPG   729600

// ---------------------------------------------------------------------------
// Fused prep:
//   z<11  -> weight matrix z into hi/lo bf16 B-fragment tables
//   z==11 -> convert fatoms/fbonds to hi/lo bf16 row pairs
//   z==12 -> pair-stage tables: binary_feats -> BINBF; Wbin -> WBF (x2)
// ---------------------------------------------------------------------------
__global__ __launch_bounds__(256) void k_prep(
    const float* __restrict__ s0, const float* __restrict__ s1,
    const float* __restrict__ s2, const float* __restrict__ s3,
    const float* __restrict__ s4, const float* __restrict__ s5,
    const float* __restrict__ s6, const float* __restrict__ s7,
    const float* __restrict__ s8, const float* __restrict__ s9,
    const float* __restrict__ s10,
    unsigned short* __restrict__ WTh, unsigned short* __restrict__ WTl,
    const float* __restrict__ fatoms, const float* __restrict__ fbonds,
    unsigned short* __restrict__ fatomsbf, unsigned short* __restrict__ fbondsbf,
    const float* __restrict__ bin, unsigned short* __restrict__ BINBF,
    const float* __restrict__ Wbin0, const float* __restrict__ Wbin1,
    unsigned short* __restrict__ WBF0, unsigned short* __restrict__ WBF1)
{
    const int z = blockIdx.z;
    if (z == 11) {
        int idx = blockIdx.x * 256 + threadIdx.x;
        if (idx < 1600 * 96) {
            int r = idx / 96, c = idx - r * 96;
            float f = (c < AF) ? fatoms[r * AF + c] : 0.f;
            unsigned short hb = f2bf(f);
            fatomsbf[r * 192 + c]      = hb;
            fatomsbf[r * 192 + 96 + c] = f2bf(f - bf2f(hb));
        } else {
            int i2 = idx - 1600 * 96;
            if (i2 < 1920 * 32) {
                int r = i2 / 32, c = i2 - r * 32;
                float f = (c < BF) ? fbonds[r * BF + c] : 0.f;
                unsigned short hb = f2bf(f);
                fbondsbf[r * 64 + c]      = hb;
                fbondsbf[r * 64 + 32 + c] = f2bf(f - bf2f(hb));
            }
        }
        return;
    }
    if (z == 12) {
        const int bx = blockIdx.x;
        if (bx < 625) {
            int p = bx * 256 + threadIdx.x;
            if (p < BB * NN * NN) {
                const float* src = bin + (size_t)p * BIN;
                unsigned short tmp[16];
#pragma unroll
                for (int k = 0; k < BIN; k++) tmp[k] = f2bf(src[k]);
#pragma unroll
                for (int k = BIN; k < 16; k++) tmp[k] = 0;
                *(uint4*)(BINBF + (size_t)p * 16) = *(uint4*)tmp;
                *(uint4*)(BINBF + (size_t)p * 16 + 8) = *(uint4*)(tmp + 8);
            }
        } else if (bx < 663) {
            int zb = bx - 625;             // 0..37
            const float* src = (zb >= 19) ? Wbin1 : Wbin0;
            unsigned short* dst = (zb >= 19) ? WBF1 : WBF0;
            int idx = (zb % 19) * 256 + threadIdx.x;
            int jj = idx & 7;
            int koct = (idx >> 3) & 1;
            int n = (idx >> 4) & 15;
            int ch = idx >> 8;
            int k = koct * 8 + jj;
            int h = ch * 16 + n;
            float f = (k < BIN && h < 300) ? src[k * 300 + h] : 0.f;
            dst[idx] = f2bf(f);
        }
        return;
    }
    const float* src; int K, kc, off;
    switch (z) {
        case 0:  src = s0;  K = AF;  kc = 3;  off = O_WATOM; break;
        case 1:  src = s1;  K = BF;  kc = 1;  off = O_WNB;   break;
        case 2:  src = s2;  K = BF;  kc = 1;  off = O_U2B;   break;
        case 3:  src = s3;  K = HH;  kc = 10; off = O_WNA;   break;
        case 4:  src = s4;  K = HH;  kc = 10; off = O_U2A;   break;
        case 5:  src = s5;  K = HH;  kc = 10; off = O_WSELF; break;
        case 6:  src = s6;  K = HH;  kc = 10; off = O_U1A;   break;
        case 7:  src = s7;  K = HH;  kc = 10; off = O_U1B;   break;
        case 8:  src = s8;  K = HH;  kc = 10; off = O_WATT;  break;
        case 9:  src = s9;  K = HH;  kc = 10; off = O_WPL;   break;
        default: src = s10; K = HH;  kc = 10; off = O_WPG;   break;
    }
    const int lim = 9728 * kc;
    int i = blockIdx.x * 256 + threadIdx.x;
    if (i < lim) {
        int jj = i & 7;
        int lane = (i >> 3) & 63;
        int rem = i >> 9;
        int kci = rem % kc;
        int ct = rem / kc;
        int k = kci * 32 + (lane >> 4) * 8 + jj;
        int col = ct * 16 + (lane & 15);
        float f = (k < K && col < 300) ? src[k * 300 + col] : 0.f;
        unsigned short hb = f2bf(f);
        WTh[off + i] = hb;
        WTl[off + i] = f2bf(f - bf2f(hb));
    }
}

// ---------------------------------------------------------------------------
// bf16x3 MFMA GEMM core. Per k-chunk: acc += ah*wl + al*wh + ah*wh.
// ---------------------------------------------------------------------------
__device__ __forceinline__ void gemm_core(
    const unsigned short* __restrict__ A, int lda, int kc, int M,
    const unsigned short* __restrict__ wthB, const unsigned short* __restrict__ wtlB,
    float* __restrict__ C, int ldc,
    const float* __restrict__ bias,
    const float* __restrict__ Add, int ldAdd, int addOff,
    int act, unsigned short* __restrict__ Cbf,
    int row0, int gcolBase)
{
    __shared__ unsigned short sa[16 * 648];
    if (row0 >= M) return;                       // block-uniform
    const int tid = threadIdx.x;
    const int lane = tid & 63;
    const int wid = tid >> 6;
    const int sR = kc * 64 + 8;

    {
        const uint4* Ag = (const uint4*)A;
        uint4* sa4 = (uint4*)sa;
        const int q4 = kc * 8;
        const int lda4 = lda >> 3;
        const int sR4 = q4 + 1;
        for (int i = tid; i < 16 * q4; i += 256) {
            int r = i / q4, q = i - r * q4;
            sa4[r * sR4 + q] = Ag[(size_t)(row0 + r) * lda4 + q];
        }
    }
    __syncthreads();

    const int ct = blockIdx.y * 4 + wid;
    if (ct >= 19) return;

    const int m = lane & 15;
    const int rq = lane >> 4;
    const int koct8 = rq * 8;
    const unsigned short* wth = wthB + (size_t)ct * kc * 512;
    const unsigned short* wtl = wtlB + (size_t)ct * kc * 512;

    floatx4 acc = {0.f, 0.f, 0.f, 0.f};
    for (int kci = 0; kci < kc; kci++) {
        short8 ah = *(const short8*)(sa + m * sR + kci * 32 + koct8);
        short8 al = *(const short8*)(sa + m * sR + kc * 32 + kci * 32 + koct8);
        short8 wh = *(const short8*)(wth + (kci * 64 + lane) * 8);
        short8 wl = *(const short8*)(wtl + (kci * 64 + lane) * 8);
        acc = __builtin_amdgcn_mfma_f32_16x16x32_bf16(ah, wl, acc, 0, 0, 0);
        acc = __builtin_amdgcn_mfma_f32_16x16x32_bf16(al, wh, acc, 0, 0, 0);
        acc = __builtin_amdgcn_mfma_f32_16x16x32_bf16(ah, wh, acc, 0, 0, 0);
    }

    const int col = ct * 16 + m;
    if (col < 300) {
        const float bv = bias ? bias[col] : 0.f;
        const int gcol = gcolBase + col;
#pragma unroll
        for (int r = 0; r < 4; r++) {
            const int grow = row0 + rq * 4 + r;
            float v = acc[r] + bv;
            if (Add) v += Add[(size_t)grow * ldAdd + addOff + col];
            if (act) v = fmaxf(v, 0.f);
            if (C) C[(size_t)grow * ldc + gcol] = v;
            if (Cbf) {
                unsigned short hb = f2bf(v);
                Cbf[(size_t)grow * 640 + col]       = hb;
                Cbf[(size_t)grow * 640 + 320 + col] = f2bf(v - bf2f(hb));
            }
        }
    }
}

// Grid: (rowTilesPadded8, 5, nW) — same-row blocks land on one XCD.
__global__ __launch_bounds__(256) void k_gemm_mfma(
    const unsigned short* __restrict__ A, int lda, int kc, int M,
    const unsigned short* __restrict__ WTh, const unsigned short* __restrict__ WTl,
    int wtStride,
    float* __restrict__ C, int ldc,
    const float* __restrict__ bias,
    const float* __restrict__ Add, int ldAdd, int addOff,
    int act, unsigned short* __restrict__ Cbf)
{
    const int widx = blockIdx.z;
    gemm_core(A, lda, kc, M,
              WTh + (size_t)widx * wtStride, WTl + (size_t)widx * wtStride,
              C, ldc, bias, Add, ldAdd, addOff, act, Cbf,
              blockIdx.x * 16, widx * 300);
}

// Fused opening GEMMs: z=0 -> h = relu(fatoms@W_atom) -> hbf;
// z=1,2 -> FB = fbonds @ [W_nei_bond | W_U2b] -> f32 ld 600.
__global__ __launch_bounds__(256) void k_gemm_first(
    const unsigned short* __restrict__ fatomsbf,
    const unsigned short* __restrict__ fbondsbf,
    const unsigned short* __restrict__ WTh, const unsigned short* __restrict__ WTl,
    unsigned short* __restrict__ hbf, float* __restrict__ FBout)
{
    const int z = blockIdx.z;
    if (z == 0) {
        gemm_core(fatomsbf, 192, 3, 1600,
                  WTh + O_WATOM, WTl + O_WATOM,
                  nullptr, 0, nullptr, nullptr, 0, 0, 1, hbf,
                  blockIdx.x * 16, 0);
    } else {
        const int w = z - 1;
        gemm_core(fbondsbf, 64, 1, 1920,
                  WTh + O_WNB + w * 9728, WTl + O_WNB + w * 9728,
                  FBout, 600, nullptr, nullptr, 0, 0, 0, nullptr,
                  blockIdx.x * 16, w * 300);
    }
}

// ---------------------------------------------------------------------------
// k_neighbor: float4-vectorized, 4 bn per block; hi/lo bf16 outputs.
// XCD swizzle: batch = bx&15.
// ---------------------------------------------------------------------------
__global__ __launch_bounds__(320) void k_neighbor(
    const float* __restrict__ HW, const float* __restrict__ FB,
    const int* __restrict__ atom_nb, const int* __restrict__ bond_nb,
    const float* __restrict__ mask_neis, const float* __restrict__ mask_atoms,
    const float* __restrict__ b_U2,
    unsigned short* __restrict__ localbf, unsigned short* __restrict__ nlbf)
{
    __shared__ int   sAn[4][MAXNB];
    __shared__ int   sBd[4][MAXNB];
    __shared__ float sM[4][MAXNB];
    const int tx = threadIdx.x;
    const int ty = threadIdx.y;
    const int bx = blockIdx.x;
    const int bn0 = ((bx & 15) * 25 + (bx >> 4)) * 4;
    const int flat = ty * 80 + tx;

    if (flat < 40)        sAn[flat / 10][flat % 10] = atom_nb[(bn0 + flat / 10) * MAXNB + flat % 10];
    else if (flat < 80)  { int f = flat - 40; sBd[f / 10][f % 10] = bond_nb[(bn0 + f / 10) * MAXNB + f % 10]; }
    else if (flat < 120) { int f = flat - 80; sM[f / 10][f % 10]  = mask_neis[(bn0 + f / 10) * MAXNB + f % 10]; }
    __syncthreads();

    if (tx >= 75) return;
    const int bn = bn0 + ty;
    const int b = bn / NN;
    const int h4 = tx;

    const float4* HW4 = (const float4*)HW;
    const float4* FB4 = (const float4*)FB;
    const float4 bu = ((const float4*)b_U2)[h4];

    float4 fnei = make_float4(0.f,0.f,0.f,0.f);
    float4 nls  = fnei;
#pragma unroll
    for (int k = 0; k < MAXNB; k++) {
        const int an = sAn[ty][k];
        const int bd = sBd[ty][k];
        const float m = sM[ty][k];
        const float4* hr = HW4 + (size_t)(b * NN + an) * 300;
        const float4* fr = FB4 + (size_t)(b * NBONDS + bd) * 150;
        float4 ha = hr[h4];
        float4 hu = hr[75 + h4];
        float4 fa = fr[h4];
        float4 fu = fr[75 + h4];
        fnei.x = fmaf(m, ha.x * fa.x, fnei.x);
        fnei.y = fmaf(m, ha.y * fa.y, fnei.y);
        fnei.z = fmaf(m, ha.z * fa.z, fnei.z);
        fnei.w = fmaf(m, ha.w * fa.w, fnei.w);
        float ux = hu.x + fu.x + bu.x;
        float uy = hu.y + fu.y + bu.y;
        float uz = hu.z + fu.z + bu.z;
        float uw = hu.w + fu.w + bu.w;
        nls.x = fmaf(m, fmaxf(ux, 0.f), nls.x);
        nls.y = fmaf(m, fmaxf(uy, 0.f), nls.y);
        nls.z = fmaf(m, fmaxf(uz, 0.f), nls.z);
        nls.w = fmaf(m, fmaxf(uw, 0.f), nls.w);
    }
    const float ma = mask_atoms[bn];
    const float4 sf = HW4[(size_t)bn * 300 + 150 + h4];
    float lv[4], nv[4];
    lv[0] = fnei.x * sf.x * ma; lv[1] = fnei.y * sf.y * ma;
    lv[2] = fnei.z * sf.z * ma; lv[3] = fnei.w * sf.w * ma;
    nv[0] = nls.x; nv[1] = nls.y; nv[2] = nls.z; nv[3] = nls.w;

    ushort4 lh, ll, nh, nl2;
    unsigned short* lhp = (unsigned short*)&lh;
    unsigned short* llp = (unsigned short*)&ll;
    unsigned short* nhp = (unsigned short*)&nh;
    unsigned short* nlp = (unsigned short*)&nl2;
#pragma unroll
    for (int c = 0; c < 4; c++) {
        unsigned short hb = f2bf(lv[c]);
        lhp[c] = hb; llp[c] = f2bf(lv[c] - bf2f(hb));
        unsigned short nb = f2bf(nv[c]);
        nhp[c] = nb; nlp[c] = f2bf(nv[c] - bf2f(nb));
    }
    *(ushort4*)(localbf + (size_t)bn * 640 + h4 * 4)       = lh;
    *(ushort4*)(localbf + (size_t)bn * 640 + 320 + h4 * 4) = ll;
    *(ushort4*)(nlbf    + (size_t)bn * 640 + h4 * 4)       = nh;
    *(ushort4*)(nlbf    + (size_t)bn * 640 + 320 + h4 * 4) = nl2;
}

// ---------------------------------------------------------------------------
// k_pair: batch-major grid (XCD-pinned); LDS stride 308 (2-way aliasing only).
// ---------------------------------------------------------------------------
__global__ __launch_bounds__(256) void k_pair(
    const float* __restrict__ R, int ldr,
    const unsigned short* __restrict__ BINBF,
    const unsigned short* __restrict__ WBF,
    const float* __restrict__ bvec,
    const float* __restrict__ Wscore, const float* __restrict__ bscore,
    float* __restrict__ outp, int mode)
{
    __shared__ float sLi[16 * 308];
    __shared__ float sLj[16 * 308];

    const int b  = blockIdx.x;                 // XCD = b & 7
    const int i0 = blockIdx.y * 16;
    const int j0 = blockIdx.z * 16;
    const int tid = threadIdx.x;
    const int lane = tid & 63;
    const int wid = tid >> 6;

    for (int idx = tid; idx < 16 * 308; idx += 256) {
        int r = idx / 308;
        int c = idx - r * 308;
        float vi = 0.f, vj = 0.f;
        if (c < 300) {
            if (i0 + r < NN) vi = R[(size_t)(b * NN + i0 + r) * ldr + c] + bvec[c];
            if (j0 + r < NN) vj = R[(size_t)(b * NN + j0 + r) * ldr + c];
        }
        sLi[idx] = vi;
        sLj[idx] = vj;
    }

    const int m = lane & 15;
    const int koct = lane >> 4;
    short8 afrag[4];
#pragma unroll
    for (int g = 0; g < 4; g++) {
        int ii = i0 + wid * 4 + g; if (ii > NN - 1) ii = NN - 1;
        int jj2 = j0 + m;          if (jj2 > NN - 1) jj2 = NN - 1;
        const size_t pidx = (size_t)((b * NN + ii) * NN + jj2);
        afrag[g] = *(const short8*)(BINBF + pidx * 16 + (koct & 1) * 8);
        if (koct >= 2) afrag[g] = short8{0,0,0,0,0,0,0,0};
    }
    __syncthreads();

    const int n = lane & 15;
    const int rquad = lane >> 4;
    const floatx4 zero = {0.f, 0.f, 0.f, 0.f};
    float su[4][4];
#pragma unroll
    for (int g = 0; g < 4; g++)
#pragma unroll
        for (int r = 0; r < 4; r++) su[g][r] = 0.f;

    for (int ch = 0; ch < 19; ch++) {
        const int h0 = ch * 16;
        short8 bfrag = {0,0,0,0,0,0,0,0};
        if (lane < 32)
            bfrag = *(const short8*)(WBF + ch * 256 + (n * 2 + koct) * 8);
        float wsv = 0.f;
        if (h0 + n < 300) wsv = Wscore[h0 + n];
#pragma unroll
        for (int g = 0; g < 4; g++) {
            floatx4 P = __builtin_amdgcn_mfma_f32_16x16x32_bf16(
                afrag[g], bfrag, zero, 0, 0, 0);
            const float liv = sLi[(wid * 4 + g) * 308 + h0 + n];
#pragma unroll
            for (int r = 0; r < 4; r++) {
                const float ljv = sLj[(rquad * 4 + r) * 308 + h0 + n];
                float u = P[r] + liv + ljv;
                su[g][r] = fmaf(fmaxf(u, 0.f), wsv, su[g][r]);
            }
        }
    }

    const float bs = bscore[0];
#pragma unroll
    for (int g = 0; g < 4; g++) {
#pragma unroll
        for (int r = 0; r < 4; r++) {
            float v = su[g][r];
            v += __shfl_xor(v, 1);
            v += __shfl_xor(v, 2);
            v += __shfl_xor(v, 4);
            v += __shfl_xor(v, 8);
            if (n == 0) {
                const int i = i0 + wid * 4 + g;
                const int j = j0 + rquad * 4 + r;
                if (i < NN && j < NN) {
                    float s = v + bs;
                    outp[(size_t)(b * NN + i) * NN + j] =
                        (mode == 0) ? (1.f / (1.f + expf(-s))) : s;
                }
            }
        }
    }
}

// ---------------------------------------------------------------------------
// ctx from hi/lo local planes; hi/lo output. 4 i-rows/block; batch-XCD swizzle.
// ---------------------------------------------------------------------------
__global__ __launch_bounds__(320) void k_ctx(
    const float* __restrict__ att, const unsigned short* __restrict__ localbf,
    unsigned short* __restrict__ ctxbf)
{
    const int bx = blockIdx.x;
    const int b = bx & 15;
    const int i0 = (bx >> 4) * 4;
    const int tid = threadIdx.x;
    __shared__ float sa[4 * NN];
    for (int idx = tid; idx < 4 * NN; idx += 320) {
        int ii = idx / NN, j = idx - ii * NN;
        sa[idx] = att[(size_t)(b * NN + i0 + ii) * NN + j];
    }
    __syncthreads();
    if (tid < HH) {
        float acc0 = 0.f, acc1 = 0.f, acc2 = 0.f, acc3 = 0.f;
        for (int j = 0; j < NN; j++) {
            const unsigned short* lr = localbf + (size_t)(b * NN + j) * 640;
            float lv = bf2f(lr[tid]) + bf2f(lr[320 + tid]);
            acc0 = fmaf(sa[j], lv, acc0);
            acc1 = fmaf(sa[NN + j], lv, acc1);
            acc2 = fmaf(sa[2 * NN + j], lv, acc2);
            acc3 = fmaf(sa[3 * NN + j], lv, acc3);
        }
        float vals[4] = {acc0, acc1, acc2, acc3};
#pragma unroll
        for (int k = 0; k < 4; k++) {
            unsigned short hb = f2bf(vals[k]);
            ctxbf[(size_t)(b * NN + i0 + k) * 640 + tid]       = hb;
            ctxbf[(size_t)(b * NN + i0 + k) * 640 + 320 + tid] = f2bf(vals[k] - bf2f(hb));
        }
    }
}

// ---------------------------------------------------------------------------
// Top-K: 1024 threads/block, per-wave histograms, wave-parallel suffix-scan.
// ---------------------------------------------------------------------------
__global__ __launch_bounds__(1024) void k_topk(
    const float* __restrict__ scores, float* __restrict__ topk_out)
{
    const int b = blockIdx.x;
    const int tid = threadIdx.x;
    const int wid = tid >> 6;
    const int lane = tid & 63;
    const float* sc = scores + (size_t)b * (NN * NN);

    __shared__ unsigned int skey[NN * NN];
    __shared__ unsigned int whist[16 * 256];
    __shared__ unsigned int hist[256];
    __shared__ unsigned int candU[KTOP];
    __shared__ int candI[KTOP];
    __shared__ int cntG;
    __shared__ int curMin;
    __shared__ unsigned int sh_pref, sh_mask;
    __shared__ int sh_kRem;
    __shared__ int sh_last;

    for (int idx = tid; idx < NN * NN; idx += 1024) {
        unsigned int u = __float_as_uint(sc[idx]);
        u = (u & 0x80000000u) ? ~u : (u | 0x80000000u);
        skey[idx] = u;
    }
    if (tid == 0) {
        sh_pref = 0u; sh_mask = 0u; sh_kRem = KTOP; cntG = 0; sh_last = -1;
    }
    __syncthreads();

    for (int pass = 0; pass < 4; pass++) {
        const int shift = 24 - 8 * pass;
        unsigned int* wh = whist + (wid << 8);
        wh[lane] = 0u; wh[lane + 64] = 0u; wh[lane + 128] = 0u; wh[lane + 192] = 0u;
        __syncthreads();
        const unsigned int pref = sh_pref, mask = sh_mask;
        for (int idx = tid; idx < NN * NN; idx += 1024) {
            unsigned int u = skey[idx];
            if ((u & mask) == pref)
                atomicAdd(&wh[(u >> shift) & 255u], 1u);
        }
        __syncthreads();
        if (tid < 256) {
            unsigned int s = 0u;
#pragma unroll
            for (int w = 0; w < 16; w++) s += whist[(w << 8) | tid];
            hist[tid] = s;
        }
        __syncthreads();
        if (wid == 0) {
            unsigned int h0 = hist[lane * 4 + 0];
            unsigned int h1 = hist[lane * 4 + 1];
            unsigned int h2 = hist[lane * 4 + 2];
            unsigned int h3 = hist[lane * 4 + 3];
            unsigned int own = h0 + h1 + h2 + h3;
            unsigned int suf = own;
#pragma unroll
            for (int off = 1; off < 64; off <<= 1) {
                unsigned int v = __shfl_down(suf, off);
                if (lane + off < 64) suf += v;
            }
            const int k = sh_kRem;
            const unsigned int above = suf - own;
            if (above < (unsigned int)k && suf >= (unsigned int)k) {
                unsigned int c = above, hb; int bsel;
                c += h3;
                if ((int)c >= k) { bsel = lane * 4 + 3; hb = h3; }
                else { c += h2;
                    if ((int)c >= k) { bsel = lane * 4 + 2; hb = h2; }
                    else { c += h1;
                        if ((int)c >= k) { bsel = lane * 4 + 1; hb = h1; }
                        else { c += h0; bsel = lane * 4; hb = h0; } } }
                sh_kRem = k - (int)(c - hb);
                sh_pref = pref | ((unsigned int)bsel << shift);
                sh_mask = mask | (0xFFu << shift);
            }
        }
        __syncthreads();
    }
    const unsigned int T = sh_pref;

    for (int idx = tid; idx < NN * NN; idx += 1024) {
        unsigned int u = skey[idx];
        if (u > T) {
            int pos = atomicAdd(&cntG, 1);
            candU[pos] = u;
            candI[pos] = idx;
        }
    }
    __syncthreads();
    const int needE = KTOP - cntG;

    for (int e = 0; e < needE; e++) {
        if (tid == 0) curMin = 0x7fffffff;
        __syncthreads();
        const int last = sh_last;
        for (int idx = tid; idx < NN * NN; idx += 1024) {
            if (skey[idx] == T && idx > last)
                atomicMin(&curMin, idx);
        }
        __syncthreads();
        if (tid == 0) {
            candU[cntG + e] = T;
            candI[cntG + e] = curMin;
            sh_last = curMin;
        }
        __syncthreads();
    }

    if (tid < KTOP) {
        const unsigned int mu = candU[tid];
        const int mi = candI[tid];
        int rank = 0;
        for (int o = 0; o < KTOP; o++) {
            unsigned int ou = candU[o];
            int oi = candI[o];
            if (ou > mu || (ou == mu && oi < mi)) rank++;
        }
        topk_out[b * KTOP + rank] = (float)mi;
    }
}

// ---------------------------------------------------------------------------
extern "C" void kernel_launch(void* const* d_in, const int* in_sizes, int n_in,
                              void* d_out, int out_size, void* d_ws, size_t ws_size,
                              hipStream_t stream) {
    const float* fatoms       = (const float*)d_in[0];
    const float* fbonds       = (const float*)d_in[1];
    const int*   atom_nb      = (const int*)d_in[2];
    const int*   bond_nb      = (const int*)d_in[3];
    const float* binary_feats = (const float*)d_in[6];
    const float* mask_neis    = (const float*)d_in[7];
    const float* mask_atoms   = (const float*)d_in[8];
    const float* W_atom       = (const float*)d_in[10];
    const float* W_nei_atom   = (const float*)d_in[11];
    const float* W_nei_bond   = (const float*)d_in[12];
    const float* W_self       = (const float*)d_in[13];
    const float* W_U2         = (const float*)d_in[14];
    const float* b_U2         = (const float*)d_in[15];
    const float* W_U1         = (const float*)d_in[16];
    const float* b_U1         = (const float*)d_in[17];
    const float* W_att_local  = (const float*)d_in[18];
    const float* W_att_bin    = (const float*)d_in[19];
    const float* b_att        = (const float*)d_in[20];
    const float* W_att_score  = (const float*)d_in[21];
    const float* b_att_score  = (const float*)d_in[22];
    const float* W_pl         = (const float*)d_in[23];
    const float* W_pg         = (const float*)d_in[24];
    const float* W_pb         = (const float*)d_in[25];
    const float* b_p          = (const float*)d_in[26];
    const float* W_out        = (const float*)d_in[27];
    const float* b_out        = (const float*)d_in[28];

    float* ws = (float*)d_ws;
    // f32 slots
    float* HW  = ws;                         // 1,920,000 f (1600 x 1200)
    float* FB  = HW + 1920000;               // 1,152,000 f (1920 x 600)
    float* LL  = FB + 1152000;               //   960,000 f (1600 x 600)
    float* LPG = LL + 960000;                //   480,000 f (1600 x 300)
    float* att = LPG + 480000;               //   160,000 f
    // shorts region (no aliasing; ws is 268 MB, we use ~36 MB)
    unsigned short* S0       = (unsigned short*)(ws + 4672000);
    unsigned short* hbf      = S0;                         // 1,024,000
    unsigned short* nlbf     = S0 + 1024000;               // 1,024,000
    unsigned short* localbf  = S0 + 2048000;               // 1,024,000
    unsigned short* WTh      = S0 + 3072000;               //   826,880
    unsigned short* WTl      = S0 + 3898880;               //   826,880
    unsigned short* ctxbf    = S0 + 4725760;               // 1,024,000
    unsigned short* BINBF    = S0 + 5749760;               // 2,560,000
    unsigned short* WBF_att  = S0 + 8309760;               //     4,864
    unsigned short* WBF_fin  = S0 + 8314624;               //     4,864
    unsigned short* fatomsbf = S0 + 8319488;               //   307,200
    unsigned short* fbondsbf = S0 + 8626688;               //   122,880

    float* out = (float*)d_out;
    float* topk_out = out + (size_t)BB * NN * NN;

    // single fused prep: weight tables (z<11) + input conv (z=11) + pair tables (z=12)
    k_prep<<<dim3(840, 1, 13), 256, 0, stream>>>(
        W_atom, W_nei_bond, W_U2 + 300 * 300, W_nei_atom, W_U2, W_self,
        W_U1, W_U1 + 300 * 300, W_att_local, W_pl, W_pg, WTh, WTl,
        fatoms, fbonds, fatomsbf, fbondsbf,
        binary_feats, BINBF, W_att_bin, W_pb, WBF_att, WBF_fin);

    // fused opening GEMMs: h -> hbf (z=0); FB (z=1,2)
    k_gemm_first<<<dim3(120, 5, 3), 256, 0, stream>>>(
        fatomsbf, fbondsbf, WTh, WTl, hbf, FB);

    for (int d = 0; d < DEPTH; d++) {
        int nW = (d == DEPTH - 1) ? 3 : 4;
        // HW = h @ [W_nei_atom | W_U2a | W_self | W_U1a] -> f32 ld 1200
        k_gemm_mfma<<<dim3(104, 5, nW), 256, 0, stream>>>(
            hbf, 640, 10, 1600, WTh + O_WNA, WTl + O_WNA, 97280,
            HW, 1200, nullptr, nullptr, 0, 0, 0, nullptr);
        // neighbor aggregate -> localbf, nlbf (hi/lo); batch-XCD swizzled
        k_neighbor<<<dim3(400), dim3(80, 4), 0, stream>>>(
            HW, FB, atom_nb, bond_nb, mask_neis, mask_atoms, b_U2,
            localbf, nlbf);
        if (d < DEPTH - 1) {
            // h = relu(HW[:,900:1200] + nl @ W_U1b + b_U1) -> hbf
            k_gemm_mfma<<<dim3(104, 5, 1), 256, 0, stream>>>(
                nlbf, 640, 10, 1600, WTh + O_U1B, WTl + O_U1B, 0,
                nullptr, 0, b_U1, HW, 1200, 900, 1, hbf);
        }
    }

    // LL = local @ [W_att_local | W_pl] -> f32 ld 600
    k_gemm_mfma<<<dim3(104, 5, 2), 256, 0, stream>>>(
        localbf, 640, 10, 1600, WTh + O_WATT, WTl + O_WATT, 97280,
        LL, 600, nullptr, nullptr, 0, 0, 0, nullptr);

    // att[b,i,j] — pair kernel, batch-major grid (XCD-pinned)
    k_pair<<<dim3(16, 7, 7), 256, 0, stream>>>(
        LL, 600, BINBF, WBF_att, b_att, W_att_score, b_att_score,
        att, 0);

    // ctx = att @ local -> ctxbf (hi/lo); XCD swizzled
    k_ctx<<<dim3(BB * 25), 320, 0, stream>>>(att, localbf, ctxbf);

    // LPG = ctx @ W_pg + LL[:,300:600] -> f32 ld 300
    k_gemm_mfma<<<dim3(104, 5, 1), 256, 0, stream>>>(
        ctxbf, 640, 10, 1600, WTh + O_WPG, WTl + O_WPG, 0,
        LPG, 300, nullptr, LL, 600, 300, 0, nullptr);

    // pair scores — pair kernel, batch-major grid (XCD-pinned)
    k_pair<<<dim3(16, 7, 7), 256, 0, stream>>>(
        LPG, 300, BINBF, WBF_fin, b_p, W_out, b_out,
        out, 1);

    // top-k indices per batch (as float values)
    k_topk<<<dim3(BB), 1024, 0, stream>>>(out, topk_out);
}